// Round 11
// baseline (264.303 us; speedup 1.0000x reference)
//
#include <hip/hip_runtime.h>

#define DIM 64
#define NCODE 1024

typedef __attribute__((ext_vector_type(8))) short bf16x8;
typedef __attribute__((ext_vector_type(4))) float f32x4;

// ---- small ws (8.3 KB) ----
#define WSO_HIST  0        // float[1024]
#define WSO_LOSS  4096     // float
#define WSO_COUNT 4100     // int
#define WSO_MAX4  4112     // float[4]
#define WSO_CBN   4160     // float[1024]

// ---- big scratch in d_out's out_xq region (dead before epilogue writes it) ----
// cbt @0 (256KB) | cbT @262144 (256KB) | list @524288 (128KB)

__device__ __forceinline__ unsigned short f2bf(float f) {
    unsigned u = __float_as_uint(f);
    unsigned r = (u + 0x7FFFu + ((u >> 16) & 1u)) >> 16;   // RNE
    return (unsigned short)r;
}

__device__ __forceinline__ void gload16(const void* g, void* l) {
    __builtin_amdgcn_global_load_lds(
        (const __attribute__((address_space(1))) unsigned int*)g,
        (__attribute__((address_space(3))) unsigned int*)l, 16, 0, 0);
}

// ---- kernel 0: prep (4 x 256): cbn, hi/lo bf16 codebook, f32 transposed codebook, zeros ----
__global__ __launch_bounds__(256) void vq_prep(const float* __restrict__ cb,
                                               char* __restrict__ ws,
                                               char* __restrict__ cbt,
                                               float* __restrict__ cbT) {
    __shared__ float red[256];
    const int t = threadIdx.x;
    const int k = blockIdx.x * 256 + t;

    float cv[64];
#pragma unroll
    for (int d = 0; d < DIM; ++d) cv[d] = cb[d * NCODE + k];

    float s = 0.f;
#pragma unroll
    for (int d = 0; d < DIM; ++d) s = fmaf(cv[d], cv[d], s);

    ((float*)(ws + WSO_CBN))[k] = s;
    ((float*)(ws + WSO_HIST))[k] = 0.f;

#pragma unroll
    for (int blk = 0; blk < 8; ++blk) {
        bf16x8 hi, lo;
#pragma unroll
        for (int e = 0; e < 8; ++e) {
            float v = cv[blk * 8 + e];
            unsigned short h = f2bf(v);
            float hf = __uint_as_float(((unsigned)h) << 16);
            lo[e] = (short)f2bf(v - hf);
            hi[e] = (short)h;
        }
        *(bf16x8*)(cbt + (size_t)k * 256 + blk * 16)       = hi;
        *(bf16x8*)(cbt + (size_t)k * 256 + 128 + blk * 16) = lo;
    }

#pragma unroll
    for (int j = 0; j < 16; ++j) {
        float4 v = {cv[4 * j], cv[4 * j + 1], cv[4 * j + 2], cv[4 * j + 3]};
        *(float4*)(cbT + (size_t)k * 64 + 4 * j) = v;
    }

    red[t] = s;
    __syncthreads();
    for (int m = 128; m > 0; m >>= 1) {
        if (t < m) red[t] = fmaxf(red[t], red[t + m]);
        __syncthreads();
    }
    if (t == 0) {
        ((float*)(ws + WSO_MAX4))[blockIdx.x] = red[0];
        if (blockIdx.x == 0) {
            *(float*)(ws + WSO_LOSS) = 0.f;
            *(int*)(ws + WSO_COUNT) = 0;
        }
    }
}

// ---- kernel 1: double-bf16 MFMA distances + (min1,min2,argmin) + flagging ----
// R11 = R10 structure (32 rows/block, dbuf bK 1-barrier/chunk, bX overlay,
// LDS 37 KB) + __launch_bounds__(256,3). Allocator map (measured): (256,4) ->
// 64 regs + spill (R6/R8); no hint -> 196 regs, 2 waves/SIMD (R10); (256,3) ->
// natural ~84, clean (R5/R7). 84-128 regs + 37 KB -> 4 blocks/CU co-resident.
__global__ __launch_bounds__(256, 3) void vq_mfma(const float* __restrict__ x,
                                                  const char* __restrict__ cbt,
                                                  char* __restrict__ ws,
                                                  unsigned short* __restrict__ list,
                                                  float* __restrict__ out_idx) {
    // LDS: bK0 16384 | bK1 16384 (bX 8KB overlays) | cbn_s 4096 | xx_s 128
    __shared__ __align__(16) char sm[36992];
    char*  bK0   = sm;
    char*  bK1   = sm + 16384;
    char*  bX    = sm + 16384;                 // overlay: rows 0..31 (8 KB)
    float* cbn_s = (float*)(sm + 32768);
    float* xx_s  = (float*)(sm + 36864);
    float* R1    = (float*)sm;                 // post-loop overlay (both bufs dead)
    float* R2v   = R1 + 128;
    int*   RIv   = (int*)(R2v + 128);

    const int t = threadIdx.x, w = t >> 6, lane = t & 63;
    const int r0 = blockIdx.x * 32;

    const float* mb4 = (const float*)(ws + WSO_MAX4);
    const float maxcbn = fmaxf(fmaxf(mb4[0], mb4[1]), fmaxf(mb4[2], mb4[3]));

#define STAGE(cc, bptr)                                                         \
    {                                                                           \
        _Pragma("unroll")                                                       \
        for (int i_ = 0; i_ < 4; ++i_) {                                        \
            int u_ = (w * 4 + i_) * 64 + lane;                                  \
            int su_ = (u_ & ~7) | ((u_ ^ (u_ >> 4)) & 7);                       \
            gload16(cbt + (size_t)(cc) * 16384 + (size_t)su_ * 16,              \
                    (bptr) + (w * 4 + i_) * 1024);                              \
        }                                                                       \
    }

    // --- issue chunk0 -> buf0 and cbn -> cbn_s FIRST (async, overlap bX VALU) ---
    STAGE(0, bK0);
    gload16((const char*)(ws + WSO_CBN) + ((size_t)w * 64 + lane) * 16, (char*)cbn_s + w * 1024);

    // --- stage bX (hi/lo bf16, XOR-swizzled): 8 threads/row, 8 dims each ---
    {
        const int row = t >> 3, q8 = t & 7;
        const float4* xp = (const float4*)(x + (size_t)(r0 + row) * DIM + q8 * 8);
        float4 v0 = xp[0], v1 = xp[1];
        float p = 0.f;
        p = fmaf(v0.x, v0.x, p); p = fmaf(v0.y, v0.y, p); p = fmaf(v0.z, v0.z, p); p = fmaf(v0.w, v0.w, p);
        p = fmaf(v1.x, v1.x, p); p = fmaf(v1.y, v1.y, p); p = fmaf(v1.z, v1.z, p); p = fmaf(v1.w, v1.w, p);
        p += __shfl_xor(p, 1);
        p += __shfl_xor(p, 2);
        p += __shfl_xor(p, 4);
        if (q8 == 0) xx_s[row] = p;

        float hv[8] = {v0.x, v0.y, v0.z, v0.w, v1.x, v1.y, v1.z, v1.w};
        bf16x8 ph, pl;
#pragma unroll
        for (int e = 0; e < 8; ++e) {
            float v = hv[e];
            unsigned short hb = f2bf(v);
            float hf = __uint_as_float(((unsigned)hb) << 16);
            ph[e] = (short)hb;
            pl[e] = (short)f2bf(v - hf);
        }
        const int s3 = (q8 ^ (row & 7)) & 7;
        *(bf16x8*)(bX + row * 256 + s3 * 16)        = ph;
        *(bf16x8*)(bX + row * 256 + (8 | s3) * 16)  = pl;
    }
    __syncthreads();   // chunk0 + cbn + bX all ready

    // --- A fragments (hi/lo) from bX into registers ---
    bf16x8 afh[2][2], afl[2][2];
#pragma unroll
    for (int rt = 0; rt < 2; ++rt)
#pragma unroll
        for (int kt = 0; kt < 2; ++kt) {
            int row = rt * 16 + (lane & 15);
            int s3 = ((kt * 4 + (lane >> 4)) ^ (row & 7)) & 7;
            afh[rt][kt] = *(const bf16x8*)(bX + row * 256 + s3 * 16);
            afl[rt][kt] = *(const bf16x8*)(bX + row * 256 + (8 | s3) * 16);
        }
    __syncthreads();   // A-frag reads done -> buf1 (bX) reusable as dbuf target

    // chunk-invariant B-fragment byte offsets
    const int cl  = w * 16 + (lane & 15);
    const int swc = cl & 7;
    const int g   = lane >> 4;
    const int ob0 = cl * 256 + ((g ^ swc) & 7) * 16;
    const int ob1 = cl * 256 + (((4 + g) ^ swc) & 7) * 16;

    float m1[8], m2[8];
    int   mi[8];
#pragma unroll
    for (int s = 0; s < 8; ++s) { m1[s] = 3.4e38f; m2[s] = 3.4e38f; mi[s] = 0; }

    for (int c = 0; c < 16; ++c) {
        char* cur = (c & 1) ? bK1 : bK0;
        if (c < 15) STAGE(c + 1, (c & 1) ? bK0 : bK1);   // prefetch, in flight during compute

        bf16x8 bh0 = *(const bf16x8*)(cur + ob0);
        bf16x8 bh1 = *(const bf16x8*)(cur + ob1);
        bf16x8 bl0 = *(const bf16x8*)(cur + ob0 + 128);
        bf16x8 bl1 = *(const bf16x8*)(cur + ob1 + 128);
        const int kg = c * 64 + cl;
        const float cbnv = cbn_s[kg];

#pragma unroll
        for (int rt = 0; rt < 2; ++rt) {
            f32x4 z = {0.f, 0.f, 0.f, 0.f};
            z = __builtin_amdgcn_mfma_f32_16x16x32_bf16(afh[rt][0], bh0, z, 0, 0, 0);
            z = __builtin_amdgcn_mfma_f32_16x16x32_bf16(afh[rt][1], bh1, z, 0, 0, 0);
            z = __builtin_amdgcn_mfma_f32_16x16x32_bf16(afl[rt][0], bh0, z, 0, 0, 0);
            z = __builtin_amdgcn_mfma_f32_16x16x32_bf16(afl[rt][1], bh1, z, 0, 0, 0);
            z = __builtin_amdgcn_mfma_f32_16x16x32_bf16(afh[rt][0], bl0, z, 0, 0, 0);
            z = __builtin_amdgcn_mfma_f32_16x16x32_bf16(afh[rt][1], bl1, z, 0, 0, 0);
#pragma unroll
            for (int v = 0; v < 4; ++v) {
                const int s = rt * 4 + v;
                float dd = fmaf(-2.f, z[v], cbnv);
                bool lt = dd < m1[s];
                m2[s] = __builtin_amdgcn_fmed3f(dd, m1[s], m2[s]);
                m1[s] = fminf(m1[s], dd);
                mi[s] = lt ? kg : mi[s];
            }
        }
        __syncthreads();   // readers of cur done + prefetch (c+1) drained
    }

    // --- fold code cols (lane&15) ---
#pragma unroll
    for (int m = 1; m <= 8; m <<= 1) {
#pragma unroll
        for (int s = 0; s < 8; ++s) {
            float o1 = __shfl_xor(m1[s], m);
            float o2 = __shfl_xor(m2[s], m);
            int   oi = __shfl_xor(mi[s], m);
            float nm2 = fminf(fminf(m2[s], o2), fmaxf(m1[s], o1));
            bool tk = (o1 < m1[s]) || (o1 == m1[s] && oi < mi[s]);
            m1[s] = fminf(m1[s], o1);
            mi[s] = tk ? oi : mi[s];
            m2[s] = nm2;
        }
    }
    // --- one writer per (row, wave) -> LDS overlay ---
    if ((lane & 15) == 0) {
        const int gq = lane >> 4;
#pragma unroll
        for (int s = 0; s < 8; ++s) {
            const int row = (s >> 2) * 16 + gq * 4 + (s & 3);
            R1[row * 4 + w]  = m1[s];
            R2v[row * 4 + w] = m2[s];
            RIv[row * 4 + w] = mi[s];
        }
    }
    __syncthreads();
    // --- combine 4 wave-partials per row; flag decision (threads 0..127) ---
    if (t < 128) {
        const int row = t >> 2, q = t & 3;
        float a1 = R1[row * 4 + q];
        float A2 = R2v[row * 4 + q];
        int   ai = RIv[row * 4 + q];
#pragma unroll
        for (int m = 1; m <= 2; m <<= 1) {
            float o1 = __shfl_xor(a1, m);
            float o2 = __shfl_xor(A2, m);
            int   oi = __shfl_xor(ai, m);
            float nm2 = fminf(fminf(A2, o2), fmaxf(a1, o1));
            bool tk = (o1 < a1) || (o1 == a1 && oi < ai);
            a1 = fminf(a1, o1);
            ai = tk ? oi : ai;
            A2 = nm2;
        }
        if (q == 0) {
            const int r = r0 + row;
            out_idx[r] = (float)ai;
            const float Bv = 1.5e-4f * sqrtf(xx_s[row] * maxcbn) + 2e-3f;
            if (A2 - a1 <= 2.f * Bv) {
                int pos = atomicAdd((int*)(ws + WSO_COUNT), 1);
                list[pos] = (unsigned short)r;
            }
        }
    }
#undef STAGE
}

// ---- kernel 2: exact f32 rescan of flagged rows (bit-identical R2 arithmetic) ----
__global__ __launch_bounds__(256, 4) void vq_refine(const float* __restrict__ x,
                                                    const float* __restrict__ cbT,
                                                    const char* __restrict__ ws,
                                                    const unsigned short* __restrict__ list,
                                                    float* __restrict__ out_idx) {
    const int N = *(const int*)(ws + WSO_COUNT);
    if ((int)blockIdx.x * 32 >= N) return;
    __shared__ float cbt_s[128 * 68];
    const float* cbn = (const float*)(ws + WSO_CBN);

    const int t = threadIdx.x;
    const int cs   = t & 7;
    const int half = (t >> 3) & 1;
    const int rs   = t >> 4;
    const int iiA = blockIdx.x * 32 + rs;
    const int iiB = iiA + 16;
    const int rA = (iiA < N) ? (int)list[iiA] : (int)list[0];
    const int rB = (iiB < N) ? (int)list[iiB] : (int)list[0];
    const int dbase = half * 32;

    float4 xA[8], xB[8];
    const float4* pA = (const float4*)(x + (size_t)rA * DIM + dbase);
    const float4* pB = (const float4*)(x + (size_t)rB * DIM + dbase);
#pragma unroll
    for (int q = 0; q < 8; ++q) { xA[q] = pA[q]; xB[q] = pB[q]; }

    float hA = 0.f, hB = 0.f;
#pragma unroll
    for (int q = 0; q < 8; ++q) {
        hA = fmaf(xA[q].x, xA[q].x, hA); hA = fmaf(xA[q].y, xA[q].y, hA);
        hA = fmaf(xA[q].z, xA[q].z, hA); hA = fmaf(xA[q].w, xA[q].w, hA);
        hB = fmaf(xB[q].x, xB[q].x, hB); hB = fmaf(xB[q].y, xB[q].y, hB);
        hB = fmaf(xB[q].z, xB[q].z, hB); hB = fmaf(xB[q].w, xB[q].w, hB);
    }
    const float xxA = hA + __shfl_xor(hA, 8);
    const float xxB = hB + __shfl_xor(hB, 8);

    float bdA = 3.4e38f, bdB = 3.4e38f;
    int   bkA = 0,       bkB = 0;

    for (int c = 0; c < 8; ++c) {
        const int k0 = c * 128;
        __syncthreads();
#pragma unroll
        for (int p = 0; p < 4; ++p) {
            const int flat = p * 2048 + t * 8;
            const int code = flat >> 6, d = flat & 63;
            float4 v0 = *(const float4*)(cbT + (size_t)k0 * 64 + flat);
            float4 v1 = *(const float4*)(cbT + (size_t)k0 * 64 + flat + 4);
            *(float4*)(&cbt_s[code * 68 + d])     = v0;
            *(float4*)(&cbt_s[code * 68 + d + 4]) = v1;
        }
        if (t < 128) cbt_s[t * 68 + 64] = cbn[k0 + t];
        __syncthreads();
#pragma unroll 2
        for (int j = 0; j < 16; ++j) {
            const int i = cs + 8 * j;
            const float4* row = (const float4*)(&cbt_s[i * 68 + dbase]);
            float a0 = 0.f, a1 = 0.f, a2 = 0.f, a3 = 0.f;
            float b0 = 0.f, b1 = 0.f, b2 = 0.f, b3 = 0.f;
#pragma unroll
            for (int q = 0; q < 8; ++q) {
                float4 cv = row[q];
                a0 = fmaf(xA[q].x, cv.x, a0); a1 = fmaf(xA[q].y, cv.y, a1);
                a2 = fmaf(xA[q].z, cv.z, a2); a3 = fmaf(xA[q].w, cv.w, a3);
                b0 = fmaf(xB[q].x, cv.x, b0); b1 = fmaf(xB[q].y, cv.y, b1);
                b2 = fmaf(xB[q].z, cv.z, b2); b3 = fmaf(xB[q].w, cv.w, b3);
            }
            float dA = (a0 + a1) + (a2 + a3);
            float dB = (b0 + b1) + (b2 + b3);
            dA += __shfl_xor(dA, 8);
            dB += __shfl_xor(dB, 8);
            const float cn = cbt_s[i * 68 + 64];
            const float distA = fmaf(-2.f, dA, xxA) + cn;
            const float distB = fmaf(-2.f, dB, xxB) + cn;
            const int k = k0 + i;
            if (distA < bdA) { bdA = distA; bkA = k; }
            if (distB < bdB) { bdB = distB; bkB = k; }
        }
    }
#pragma unroll
    for (int m = 1; m <= 4; m <<= 1) {
        float odA = __shfl_xor(bdA, m); int okA = __shfl_xor(bkA, m);
        float odB = __shfl_xor(bdB, m); int okB = __shfl_xor(bkB, m);
        if (odA < bdA || (odA == bdA && okA < bkA)) { bdA = odA; bkA = okA; }
        if (odB < bdB || (odB == bdB && okB < bkB)) { bdB = odB; bkB = okB; }
    }
    if ((t & 15) == 0) {
        if (iiA < N) out_idx[rA] = (float)bkA;
        if (iiB < N) out_idx[rB] = (float)bkB;
    }
}

// ---- kernel 3: epilogue: gather, straight-through write, loss, histogram ----
__global__ __launch_bounds__(256) void vq_epilogue(const float* __restrict__ x,
                                                   const float* __restrict__ cb,
                                                   const float* __restrict__ idx_f,
                                                   float* __restrict__ out_xq,
                                                   char* __restrict__ ws) {
    const int t = threadIdx.x;
    const int row = blockIdx.x * 64 + (t >> 2), q = t & 3;
    const int k = (int)idx_f[row];
    const float4* xp = (const float4*)(x + (size_t)row * DIM + q * 16);
    float4* op = (float4*)(out_xq + (size_t)row * DIM + q * 16);
    float lsum = 0.f;
#pragma unroll
    for (int j = 0; j < 4; ++j) {
        float4 xv = xp[j];
        const int d0 = q * 16 + 4 * j;
        float q0 = cb[(d0 + 0) * NCODE + k];
        float q1 = cb[(d0 + 1) * NCODE + k];
        float q2 = cb[(d0 + 2) * NCODE + k];
        float q3 = cb[(d0 + 3) * NCODE + k];
        float e0 = q0 - xv.x, e1 = q1 - xv.y, e2 = q2 - xv.z, e3 = q3 - xv.w;
        float4 o;
        o.x = xv.x + e0; o.y = xv.y + e1; o.z = xv.z + e2; o.w = xv.w + e3;
        op[j] = o;
        lsum = fmaf(e0, e0, lsum); lsum = fmaf(e1, e1, lsum);
        lsum = fmaf(e2, e2, lsum); lsum = fmaf(e3, e3, lsum);
    }
    if (q == 0) atomicAdd((float*)(ws + WSO_HIST) + k, 1.0f);
#pragma unroll
    for (int off = 1; off < 64; off <<= 1) lsum += __shfl_xor(lsum, off);
    if ((t & 63) == 0) atomicAdd((float*)(ws + WSO_LOSS), lsum);
}

// ---- kernel 4: EMA + loss finalize ----
__global__ __launch_bounds__(256) void vq_final(const float* __restrict__ cf,
                                                const char* __restrict__ ws,
                                                float* __restrict__ out_loss,
                                                float* __restrict__ out_freq) {
    int k = blockIdx.x * 256 + threadIdx.x;
    out_freq[k] = 0.95f * cf[k] + 0.05f * ((const float*)(ws + WSO_HIST))[k];
    if (k == 0) {
        float m = *(const float*)(ws + WSO_LOSS) / 4194304.0f;
        out_loss[0] = m + m;
    }
}

extern "C" void kernel_launch(void* const* d_in, const int* in_sizes, int n_in,
                              void* d_out, int out_size, void* d_ws, size_t ws_size,
                              hipStream_t stream) {
    const float* x  = (const float*)d_in[0];   // [16,4096,64]
    const float* cb = (const float*)d_in[1];   // [64,1024]
    const float* cf = (const float*)d_in[2];   // [1024]

    float* out      = (float*)d_out;
    float* out_xq   = out;                     // 4,194,304 floats
    float* out_idx  = out + 4194304;           // 65,536
    float* out_loss = out + 4194304 + 65536;   // 1
    float* out_freq = out_loss + 1;            // 1024

    char* ws = (char*)d_ws;                    // 8,256 bytes used

    char*           cbt  = (char*)d_out;                               // 262,144 B
    float*          cbT  = (float*)((char*)d_out + 262144);            // 262,144 B
    unsigned short* list = (unsigned short*)((char*)d_out + 524288);   // 131,072 B

    vq_prep    <<<4,    256, 0, stream>>>(cb, ws, cbt, cbT);
    vq_mfma    <<<2048, 256, 0, stream>>>(x, cbt, ws, list, out_idx);
    vq_refine  <<<2048, 256, 0, stream>>>(x, cbT, ws, list, out_idx);
    vq_epilogue<<<1024, 256, 0, stream>>>(x, cb, out_idx, out_xq, ws);
    vq_final   <<<4,    256, 0, stream>>>(cf, ws, out_loss, out_freq);
}

// Round 12
// 138.353 us; speedup vs baseline: 1.9103x; 1.9103x over previous
//
#include <hip/hip_runtime.h>

#define DIM 64
#define NCODE 1024

typedef __attribute__((ext_vector_type(8))) short bf16x8;
typedef __attribute__((ext_vector_type(4))) float f32x4;

// ---- small ws (8.3 KB) ----
#define WSO_HIST  0        // float[1024]
#define WSO_LOSS  4096     // float
#define WSO_COUNT 4100     // int
#define WSO_MAX4  4112     // float[4]
#define WSO_CBN   4160     // float[1024]

// ---- big scratch in d_out's out_xq region (dead before epilogue writes it) ----
// cbt (bf16 hi/lo codebook) @0 (262144 B) | list (u16 flagged rows) @262144 (131072 B)

__device__ __forceinline__ unsigned short f2bf(float f) {
    unsigned u = __float_as_uint(f);
    unsigned r = (u + 0x7FFFu + ((u >> 16) & 1u)) >> 16;   // RNE
    return (unsigned short)r;
}

__device__ __forceinline__ void gload16(const void* g, void* l) {
    __builtin_amdgcn_global_load_lds(
        (const __attribute__((address_space(1))) unsigned int*)g,
        (__attribute__((address_space(3))) unsigned int*)l, 16, 0, 0);
}

// ---- kernel 0: prep (4 x 256): cbn, hi/lo bf16 codebook, zeros ----
__global__ __launch_bounds__(256) void vq_prep(const float* __restrict__ cb,
                                               char* __restrict__ ws,
                                               char* __restrict__ cbt) {
    __shared__ float red[256];
    const int t = threadIdx.x;
    const int k = blockIdx.x * 256 + t;

    float cv[64];
#pragma unroll
    for (int d = 0; d < DIM; ++d) cv[d] = cb[d * NCODE + k];

    float s = 0.f;
#pragma unroll
    for (int d = 0; d < DIM; ++d) s = fmaf(cv[d], cv[d], s);

    ((float*)(ws + WSO_CBN))[k] = s;
    ((float*)(ws + WSO_HIST))[k] = 0.f;

#pragma unroll
    for (int blk = 0; blk < 8; ++blk) {
        bf16x8 hi, lo;
#pragma unroll
        for (int e = 0; e < 8; ++e) {
            float v = cv[blk * 8 + e];
            unsigned short h = f2bf(v);
            float hf = __uint_as_float(((unsigned)h) << 16);
            lo[e] = (short)f2bf(v - hf);
            hi[e] = (short)h;
        }
        *(bf16x8*)(cbt + (size_t)k * 256 + blk * 16)       = hi;
        *(bf16x8*)(cbt + (size_t)k * 256 + 128 + blk * 16) = lo;
    }

    red[t] = s;
    __syncthreads();
    for (int m = 128; m > 0; m >>= 1) {
        if (t < m) red[t] = fmaxf(red[t], red[t + m]);
        __syncthreads();
    }
    if (t == 0) {
        ((float*)(ws + WSO_MAX4))[blockIdx.x] = red[0];
        if (blockIdx.x == 0) {
            *(float*)(ws + WSO_LOSS) = 0.f;
            *(int*)(ws + WSO_COUNT) = 0;
        }
    }
}

// ---- kernel 1: double-bf16 MFMA distances + (min1,min2,argmin) + flagging ----
// R5 kernel VERBATIM (best measured: 66-75us, VGPR 84, no spill, twice reproduced).
// 64 rows/block, 16 chunks of 64 codes, double-buffered bK, 1 barrier/chunk.
__global__ __launch_bounds__(256, 2) void vq_mfma(const float* __restrict__ x,
                                                  const char* __restrict__ cbt,
                                                  char* __restrict__ ws,
                                                  unsigned short* __restrict__ list,
                                                  float* __restrict__ out_idx) {
    // LDS: bK 2x16384 | bX 16384 (reduce scratch overlays) | cbn_s 4096 | xx_s 256
    __shared__ __align__(16) char sm[53504];
    char*  bK    = sm;
    char*  bX    = sm + 32768;
    float* cbn_s = (float*)(sm + 49152);
    float* xx_s  = (float*)(sm + 53248);
    float* R1    = (float*)(sm + 32768);          // overlays bX (dead after af loads)
    float* R2v   = R1 + 256;
    int*   RIv   = (int*)(R2v + 256);

    const int t = threadIdx.x, w = t >> 6, lane = t & 63;
    const int r0 = blockIdx.x * 64;

    const float* mb4 = (const float*)(ws + WSO_MAX4);
    const float maxcbn = fmaxf(fmaxf(mb4[0], mb4[1]), fmaxf(mb4[2], mb4[3]));

    // --- stage bX (hi/lo bf16, XOR-swizzled) + xx ---
    {
        const int row = t >> 2, q = t & 3;
        const float4* xp = (const float4*)(x + (size_t)(r0 + row) * DIM + q * 16);
        float4 v0 = xp[0], v1 = xp[1], v2 = xp[2], v3 = xp[3];
        float p = 0.f;
        p = fmaf(v0.x, v0.x, p); p = fmaf(v0.y, v0.y, p); p = fmaf(v0.z, v0.z, p); p = fmaf(v0.w, v0.w, p);
        p = fmaf(v1.x, v1.x, p); p = fmaf(v1.y, v1.y, p); p = fmaf(v1.z, v1.z, p); p = fmaf(v1.w, v1.w, p);
        p = fmaf(v2.x, v2.x, p); p = fmaf(v2.y, v2.y, p); p = fmaf(v2.z, v2.z, p); p = fmaf(v2.w, v2.w, p);
        p = fmaf(v3.x, v3.x, p); p = fmaf(v3.y, v3.y, p); p = fmaf(v3.z, v3.z, p); p = fmaf(v3.w, v3.w, p);
        p += __shfl_xor(p, 1);
        p += __shfl_xor(p, 2);
        if (q == 0) xx_s[row] = p;

        float hv[16] = {v0.x, v0.y, v0.z, v0.w, v1.x, v1.y, v1.z, v1.w,
                        v2.x, v2.y, v2.z, v2.w, v3.x, v3.y, v3.z, v3.w};
        bf16x8 ph[2], pl[2];
#pragma unroll
        for (int h = 0; h < 2; ++h)
#pragma unroll
            for (int e = 0; e < 8; ++e) {
                float v = hv[h * 8 + e];
                unsigned short hb = f2bf(v);
                float hf = __uint_as_float(((unsigned)hb) << 16);
                ph[h][e] = (short)hb;
                pl[h][e] = (short)f2bf(v - hf);
            }
        const int sw = row & 7;
        char* base = bX + row * 256;
#pragma unroll
        for (int h = 0; h < 2; ++h) {
            int s3 = (2 * q + h) ^ sw;
            *(bf16x8*)(base + (s3 & 7) * 16)        = ph[h];
            *(bf16x8*)(base + (8 | (s3 & 7)) * 16)  = pl[h];
        }
    }

    // --- async loads: cbn (once) + chunk 0 ---
    gload16((const char*)(ws + WSO_CBN) + ((size_t)w * 64 + lane) * 16, (char*)cbn_s + w * 1024);
#define STAGE(cc, buf)                                                          \
    {                                                                           \
        _Pragma("unroll")                                                       \
        for (int i_ = 0; i_ < 4; ++i_) {                                        \
            int u_ = (w * 4 + i_) * 64 + lane;                                  \
            int su_ = (u_ & ~7) | ((u_ ^ (u_ >> 4)) & 7);                       \
            gload16(cbt + (size_t)(cc) * 16384 + (size_t)su_ * 16,              \
                    (buf) + (w * 4 + i_) * 1024);                               \
        }                                                                       \
    }
    STAGE(0, bK);
    __syncthreads();   // bX + cbn + chunk0 ready

    // --- A fragments (hi/lo) from bX ---
    bf16x8 afh[4][2], afl[4][2];
#pragma unroll
    for (int rt = 0; rt < 4; ++rt)
#pragma unroll
        for (int kt = 0; kt < 2; ++kt) {
            int row = rt * 16 + (lane & 15);
            int s3 = ((kt * 4 + (lane >> 4)) ^ (row & 7)) & 7;
            afh[rt][kt] = *(const bf16x8*)(bX + row * 256 + s3 * 16);
            afl[rt][kt] = *(const bf16x8*)(bX + row * 256 + (8 | s3) * 16);
        }

    float m1[16], m2[16];
    int   mi[16];
#pragma unroll
    for (int s = 0; s < 16; ++s) { m1[s] = 3.4e38f; m2[s] = 3.4e38f; mi[s] = 0; }

    for (int c = 0; c < 16; ++c) {
        const char* cur = bK + (c & 1) * 16384;
        if (c < 15) STAGE(c + 1, bK + ((c + 1) & 1) * 16384);

        const int cl = w * 16 + (lane & 15);
        const int swc = cl & 7;
        const int g = lane >> 4;
        const int s30 = (g ^ swc) & 7;
        const int s31 = ((4 + g) ^ swc) & 7;
        bf16x8 bh0 = *(const bf16x8*)(cur + cl * 256 + s30 * 16);
        bf16x8 bh1 = *(const bf16x8*)(cur + cl * 256 + s31 * 16);
        bf16x8 bl0 = *(const bf16x8*)(cur + cl * 256 + (8 | s30) * 16);
        bf16x8 bl1 = *(const bf16x8*)(cur + cl * 256 + (8 | s31) * 16);
        const int kg = c * 64 + cl;
        const float cbnv = cbn_s[kg];

#pragma unroll
        for (int rt = 0; rt < 4; ++rt) {
            f32x4 z = {0.f, 0.f, 0.f, 0.f};
            z = __builtin_amdgcn_mfma_f32_16x16x32_bf16(afh[rt][0], bh0, z, 0, 0, 0);
            z = __builtin_amdgcn_mfma_f32_16x16x32_bf16(afh[rt][1], bh1, z, 0, 0, 0);
            z = __builtin_amdgcn_mfma_f32_16x16x32_bf16(afl[rt][0], bh0, z, 0, 0, 0);
            z = __builtin_amdgcn_mfma_f32_16x16x32_bf16(afl[rt][1], bh1, z, 0, 0, 0);
            z = __builtin_amdgcn_mfma_f32_16x16x32_bf16(afh[rt][0], bl0, z, 0, 0, 0);
            z = __builtin_amdgcn_mfma_f32_16x16x32_bf16(afh[rt][1], bl1, z, 0, 0, 0);
#pragma unroll
            for (int v = 0; v < 4; ++v) {
                const int s = rt * 4 + v;
                float dd = fmaf(-2.f, z[v], cbnv);
                bool lt = dd < m1[s];
                m2[s] = fminf(m2[s], fmaxf(m1[s], dd));
                m1[s] = fminf(m1[s], dd);
                mi[s] = lt ? kg : mi[s];
            }
        }
        __syncthreads();
    }

    // --- stage A: butterfly reduce over lane&15 ---
#pragma unroll
    for (int m = 1; m <= 8; m <<= 1) {
#pragma unroll
        for (int s = 0; s < 16; ++s) {
            float o1 = __shfl_xor(m1[s], m);
            float o2 = __shfl_xor(m2[s], m);
            int   oi = __shfl_xor(mi[s], m);
            float nm2 = fminf(fminf(m2[s], o2), fmaxf(m1[s], o1));
            bool tk = (o1 < m1[s]) || (o1 == m1[s] && oi < mi[s]);
            m1[s] = fminf(m1[s], o1);
            mi[s] = tk ? oi : mi[s];
            m2[s] = nm2;
        }
    }
    // --- stage B: one writer per (row, wave) ---
    if ((lane & 15) == 0) {
        const int gq = lane >> 4;
#pragma unroll
        for (int s = 0; s < 16; ++s) {
            const int row = (s >> 2) * 16 + gq * 4 + (s & 3);
            R1[row * 4 + w]  = m1[s];
            R2v[row * 4 + w] = m2[s];
            RIv[row * 4 + w] = mi[s];
        }
    }
    __syncthreads();
    // --- stage C: combine 4 wave-partials; flag decision ---
    {
        const int row = t >> 2, q = t & 3;
        float a1 = R1[row * 4 + q];
        float A2 = R2v[row * 4 + q];
        int   ai = RIv[row * 4 + q];
#pragma unroll
        for (int m = 1; m <= 2; m <<= 1) {
            float o1 = __shfl_xor(a1, m);
            float o2 = __shfl_xor(A2, m);
            int   oi = __shfl_xor(ai, m);
            float nm2 = fminf(fminf(A2, o2), fmaxf(a1, o1));
            bool tk = (o1 < a1) || (o1 == a1 && oi < ai);
            a1 = fminf(a1, o1);
            ai = tk ? oi : ai;
            A2 = nm2;
        }
        if (q == 0) {
            const int r = r0 + row;
            out_idx[r] = (float)ai;
            const float Bv = 1.5e-4f * sqrtf(xx_s[row] * maxcbn) + 2e-3f;
            if (A2 - a1 <= 2.f * Bv) {
                int pos = atomicAdd((int*)(ws + WSO_COUNT), 1);
                list[pos] = (unsigned short)r;
            }
        }
    }
#undef STAGE
}

// ---- kernel 2: refine v3 — wave per flagged row, d-major coalesced from L2 ----
// Lane handles code kb+lane per batch; cb[d*1024+kb+lane] is 256B coalesced.
// x row hoisted to 64 statically-indexed registers. Grid-stride over list.
__global__ void vq_refine(const float* __restrict__ x,
                          const float* __restrict__ cb,
                          const char* __restrict__ ws,
                          const unsigned short* __restrict__ list,
                          float* __restrict__ out_idx) {
    const int N = *(const int*)(ws + WSO_COUNT);
    const float* cbn = (const float*)(ws + WSO_CBN);
    __shared__ float rowx[4][64];
    const int t = threadIdx.x, w = t >> 6, lane = t & 63;

    for (int base = blockIdx.x * 4; base < N; base += (int)gridDim.x * 4) {
        const int ii = base + w;
        const bool valid = ii < N;
        const int r = valid ? (int)list[ii] : (int)list[0];

        __syncthreads();                       // prev iteration's rowx readers done
        const float xv = x[(size_t)r * DIM + lane];   // coalesced 256B/wave
        rowx[w][lane] = xv;
        float p = xv * xv;
#pragma unroll
        for (int m = 1; m < 64; m <<= 1) p += __shfl_xor(p, m);
        const float xx = p;
        __syncthreads();                       // rowx visible

        // hoist x row into registers (static indices -> stays in VGPRs)
        float xr[64];
#pragma unroll
        for (int d = 0; d < 64; ++d) xr[d] = rowx[w][d];

        float bd = 3.4e38f;
        int   bk = 0;
        for (int kb = 0; kb < NCODE; kb += 64) {
            float d0 = 0.f, d1 = 0.f, d2 = 0.f, d3 = 0.f;
            const float* cp = cb + kb + lane;
#pragma unroll
            for (int d = 0; d < 64; d += 4) {
                d0 = fmaf(xr[d + 0], cp[(d + 0) * NCODE], d0);
                d1 = fmaf(xr[d + 1], cp[(d + 1) * NCODE], d1);
                d2 = fmaf(xr[d + 2], cp[(d + 2) * NCODE], d2);
                d3 = fmaf(xr[d + 3], cp[(d + 3) * NCODE], d3);
            }
            const float dot = (d0 + d1) + (d2 + d3);
            const float dist = fmaf(-2.f, dot, xx) + cbn[kb + lane];
            const int k = kb + lane;
            if (dist < bd) { bd = dist; bk = k; }   // per-lane k ascending: first-min
        }
#pragma unroll
        for (int m = 1; m < 64; m <<= 1) {
            float od = __shfl_xor(bd, m);
            int   ok = __shfl_xor(bk, m);
            if (od < bd || (od == bd && ok < bk)) { bd = od; bk = ok; }
        }
        if (lane == 0 && valid) out_idx[r] = (float)bk;
    }
}

// ---- kernel 3: epilogue: gather, straight-through write, loss, histogram ----
__global__ __launch_bounds__(256) void vq_epilogue(const float* __restrict__ x,
                                                   const float* __restrict__ cb,
                                                   const float* __restrict__ idx_f,
                                                   float* __restrict__ out_xq,
                                                   char* __restrict__ ws) {
    const int t = threadIdx.x;
    const int row = blockIdx.x * 64 + (t >> 2), q = t & 3;
    const int k = (int)idx_f[row];
    const float4* xp = (const float4*)(x + (size_t)row * DIM + q * 16);
    float4* op = (float4*)(out_xq + (size_t)row * DIM + q * 16);
    float lsum = 0.f;
#pragma unroll
    for (int j = 0; j < 4; ++j) {
        float4 xv = xp[j];
        const int d0 = q * 16 + 4 * j;
        float q0 = cb[(d0 + 0) * NCODE + k];
        float q1 = cb[(d0 + 1) * NCODE + k];
        float q2 = cb[(d0 + 2) * NCODE + k];
        float q3 = cb[(d0 + 3) * NCODE + k];
        float e0 = q0 - xv.x, e1 = q1 - xv.y, e2 = q2 - xv.z, e3 = q3 - xv.w;
        float4 o;
        o.x = xv.x + e0; o.y = xv.y + e1; o.z = xv.z + e2; o.w = xv.w + e3;
        op[j] = o;
        lsum = fmaf(e0, e0, lsum); lsum = fmaf(e1, e1, lsum);
        lsum = fmaf(e2, e2, lsum); lsum = fmaf(e3, e3, lsum);
    }
    if (q == 0) atomicAdd((float*)(ws + WSO_HIST) + k, 1.0f);
#pragma unroll
    for (int off = 1; off < 64; off <<= 1) lsum += __shfl_xor(lsum, off);
    if ((t & 63) == 0) atomicAdd((float*)(ws + WSO_LOSS), lsum);
}

// ---- kernel 4: EMA + loss finalize ----
__global__ __launch_bounds__(256) void vq_final(const float* __restrict__ cf,
                                                const char* __restrict__ ws,
                                                float* __restrict__ out_loss,
                                                float* __restrict__ out_freq) {
    int k = blockIdx.x * 256 + threadIdx.x;
    out_freq[k] = 0.95f * cf[k] + 0.05f * ((const float*)(ws + WSO_HIST))[k];
    if (k == 0) {
        float m = *(const float*)(ws + WSO_LOSS) / 4194304.0f;
        out_loss[0] = m + m;
    }
}

extern "C" void kernel_launch(void* const* d_in, const int* in_sizes, int n_in,
                              void* d_out, int out_size, void* d_ws, size_t ws_size,
                              hipStream_t stream) {
    const float* x  = (const float*)d_in[0];   // [16,4096,64]
    const float* cb = (const float*)d_in[1];   // [64,1024]
    const float* cf = (const float*)d_in[2];   // [1024]

    float* out      = (float*)d_out;
    float* out_xq   = out;                     // 4,194,304 floats
    float* out_idx  = out + 4194304;           // 65,536
    float* out_loss = out + 4194304 + 65536;   // 1
    float* out_freq = out_loss + 1;            // 1024

    char* ws = (char*)d_ws;                    // 8,256 bytes used

    // big scratch inside out_xq (free until epilogue overwrites it)
    char*           cbt  = (char*)d_out;                               // 262,144 B
    unsigned short* list = (unsigned short*)((char*)d_out + 262144);   // 131,072 B

    vq_prep    <<<4,    256, 0, stream>>>(cb, ws, cbt);
    vq_mfma    <<<1024, 256, 0, stream>>>(x, cbt, ws, list, out_idx);
    vq_refine  <<<2048, 256, 0, stream>>>(x, cb, ws, list, out_idx);
    vq_epilogue<<<1024, 256, 0, stream>>>(x, cb, out_idx, out_xq, ws);
    vq_final   <<<4,    256, 0, stream>>>(cf, ws, out_loss, out_freq);
}